// Round 6
// baseline (115.100 us; speedup 1.0000x reference)
//
#include <hip/hip_runtime.h>

// DTFormer: B=64, L=1024, S=8, D=128
// Two-kernel pipeline:
//  K1 prep (192 blocks x 1024):
//    blocks 0..63   : per-batch LDS histogram over packed (id,snap) keys ->
//                     per-unit pre-shifted table row base (row<<5); units with
//                     count>=16 (never on this input) get bit31 + compact list
//    blocks 64..191 : Phi table [8][16][16][128], one row per wave, shuffle-reduce
//  K2 gather+fixup (4096+64 blocks):
//    blocks 0..4095 : rowinfo -> table float4 -> single NT 16B store,
//                     predicated off for slow units (race-free vs fixup)
//    blocks 4096+   : per-batch exact recompute of slow units (no-op here)

#define LSEQ    1024
#define NBATCH  64
#define DDIM    128
#define NKEYS   16384
#define CMAX    16
#define NUNITS  (2 * NBATCH * LSEQ)          // 131072
#define NQUADS  (NUNITS * (DDIM / 4))        // 4194304 float4s of output
#define NGBLK   (NQUADS / 1024)              // 4096 gather blocks

typedef float f4 __attribute__((ext_vector_type(4)));

__device__ __forceinline__ unsigned int umin_u(unsigned int a, unsigned int b) {
    return a < b ? a : b;
}

// ------------------------------ K1 ----------------------------------------
__global__ __launch_bounds__(1024) void prep_kernel(
    const int* __restrict__ src_ids, const int* __restrict__ dst_ids,
    const int* __restrict__ src_sn,  const int* __restrict__ dst_sn,
    const float* __restrict__ agg_w1, const float* __restrict__ agg_b1,
    const float* __restrict__ agg_w2, const float* __restrict__ agg_b2,
    const float* __restrict__ enc_w1, const float* __restrict__ enc_b1,
    const float* __restrict__ enc_w2, const float* __restrict__ enc_b2,
    unsigned int* __restrict__ rowinfo, float* __restrict__ table,
    unsigned int* __restrict__ slowcnt, uint2* __restrict__ slowbuf)
{
    __shared__ unsigned int hist[NKEYS];   // src count lo16, dst count hi16
    __shared__ unsigned int slot;

    if (blockIdx.x < NBATCH) {
        // ---- per-batch histogram + rowinfo + slow list ----
        const int b = blockIdx.x;
        const int t = threadIdx.x;

        uint4* h4 = (uint4*)hist;
        const uint4 z = make_uint4(0u, 0u, 0u, 0u);
        #pragma unroll
        for (int i = 0; i < NKEYS / 4 / 1024; ++i) h4[t + i * 1024] = z;
        if (t == 0) slot = 0u;
        __syncthreads();

        const int base = b * LSEQ;
        const int sid = src_ids[base + t];
        const int ssn = src_sn[base + t];
        const int did = dst_ids[base + t];
        const int dsn = dst_sn[base + t];

        const unsigned int ssnz = (unsigned int)((ssn - 1) & 7);
        const unsigned int dsnz = (unsigned int)((dsn - 1) & 7);
        unsigned int skey = (unsigned int)(sid * 8) + ssnz;
        unsigned int dkey = (unsigned int)(did * 8) + dsnz;
        if (skey >= NKEYS) skey = NKEYS - 1;   // never hit: id < 2000
        if (dkey >= NKEYS) dkey = NKEYS - 1;

        atomicAdd(&hist[skey], 1u);
        atomicAdd(&hist[dkey], 65536u);
        __syncthreads();

        const unsigned int hs = hist[skey];
        const unsigned int hd = hist[dkey];
        const unsigned int sv = (sid != 0) ? 1u : 0u;
        const unsigned int dv = (did != 0) ? 1u : 0u;
        const unsigned int sc0 = (hs & 0xffffu) * sv;   // src self
        const unsigned int sc1 = (hs >> 16) * sv;       // src cross
        const unsigned int dc0 = (hd >> 16) * dv;       // dst self
        const unsigned int dc1 = (hd & 0xffffu) * dv;   // dst cross

        const unsigned int sslow = (sc0 >= CMAX || sc1 >= CMAX) ? 0x80000000u : 0u;
        const unsigned int dslow = (dc0 >= CMAX || dc1 >= CMAX) ? 0x80000000u : 0u;

        // pre-shifted quad base: ((snz*16+c0)*16+c1) << 5 ; bit31 = slow
        rowinfo[base + t] = sslow |
            (((ssnz << 8) | (umin_u(sc0, CMAX - 1) << 4) | umin_u(sc1, CMAX - 1)) << 5);
        rowinfo[NBATCH * LSEQ + base + t] = dslow |
            (((dsnz << 8) | (umin_u(dc0, CMAX - 1) << 4) | umin_u(dc1, CMAX - 1)) << 5);

        if (sslow) {
            const unsigned int e = atomicAdd(&slot, 1u);
            slowbuf[b * 2048 + e] =
                make_uint2((unsigned int)(base + t),
                           sc0 | (sc1 << 11) | (ssnz << 22));
        }
        if (dslow) {
            const unsigned int e = atomicAdd(&slot, 1u);
            slowbuf[b * 2048 + e] =
                make_uint2((unsigned int)(NBATCH * LSEQ + base + t),
                           dc0 | (dc1 << 11) | (dsnz << 22));
        }
        __syncthreads();
        if (t == 0) slowcnt[b] = slot;
    } else {
        // ---- Phi table: one row per wave, shuffle-reduce ----
        const int wave = threadIdx.x >> 6;
        const int lane = threadIdx.x & 63;
        const int r = (blockIdx.x - NBATCH) * 16 + wave;   // [0, 2048)
        const int sn = r >> 8;
        const int c0 = (r >> 4) & 15;
        const int c1 = r & 15;

        float p0 = 0.0f, p1 = 0.0f;
        #pragma unroll
        for (int half = 0; half < 2; ++half) {
            const int d = lane + half * 64;
            const float w1d = agg_w1[sn * DDIM + d];
            const float b1d = agg_b1[d];
            const float h = fmaxf((float)c0 * w1d + b1d, 0.0f)
                          + fmaxf((float)c1 * w1d + b1d, 0.0f);
            p0 += h * agg_w2[d * 2 + 0];
            p1 += h * agg_w2[d * 2 + 1];
        }
        #pragma unroll
        for (int m = 32; m; m >>= 1) {
            p0 += __shfl_xor(p0, m, 64);
            p1 += __shfl_xor(p1, m, 64);
        }
        const float y0 = agg_b2[0] + 0.5f * p0;
        const float y1 = agg_b2[1] + 0.5f * p1;

        float a0 = 2.0f * enc_b2[lane];
        float a1 = 2.0f * enc_b2[lane + 64];
        #pragma unroll 4
        for (int k = 0; k < DDIM; ++k) {
            const float w1e = enc_w1[k], b1e = enc_b1[k];
            const float gk = fmaxf(y0 * w1e + b1e, 0.0f)
                           + fmaxf(y1 * w1e + b1e, 0.0f);
            a0 += gk * enc_w2[k * DDIM + lane];
            a1 += gk * enc_w2[k * DDIM + lane + 64];
        }
        table[r * DDIM + lane]      = a0;
        table[r * DDIM + lane + 64] = a1;
    }
}

// ------------------------- K2: gather + fixup ------------------------------
__global__ __launch_bounds__(256) void gather_fix_kernel(
    const unsigned int* __restrict__ rowinfo,
    const float* __restrict__ table,
    const unsigned int* __restrict__ slowcnt,
    const uint2* __restrict__ slowbuf,
    const float* __restrict__ agg_w1, const float* __restrict__ agg_b1,
    const float* __restrict__ agg_w2, const float* __restrict__ agg_b2,
    const float* __restrict__ enc_w1, const float* __restrict__ enc_b1,
    const float* __restrict__ enc_w2, const float* __restrict__ enc_b2,
    float* __restrict__ out)
{
    f4* out4 = (f4*)out;

    if (blockIdx.x < NGBLK) {
        // ---- gather: predicated NT store (slow units skipped -> race-free) --
        const f4* table4 = (const f4*)table;
        const int base = blockIdx.x * 1024 + threadIdx.x;   // 1024 quads/block
        #pragma unroll
        for (int k = 0; k < 4; ++k) {
            const int gt = base + k * 256;
            const unsigned int info = rowinfo[gt >> 5];
            if (!(info & 0x80000000u)) {
                const f4 v = table4[info + (gt & 31)];
                __builtin_nontemporal_store(v, &out4[gt]);
            }
        }
    } else {
        // ---- fixup: exact recompute of slow units (no-op on this input) ----
        const int b = blockIdx.x - NGBLK;
        const unsigned int n = slowcnt[b];
        if (n == 0u) return;

        const int q = threadIdx.x & 31;
        for (unsigned int e0 = 0; e0 < n; e0 += 8) {
            const unsigned int e = e0 + (threadIdx.x >> 5);
            if (e >= n) continue;
            const uint2 ent = slowbuf[b * 2048 + e];
            const unsigned int c0  = ent.y & 0x7FFu;
            const unsigned int c1  = (ent.y >> 11) & 0x7FFu;
            const unsigned int snz = (ent.y >> 22) & 7u;

            float s0 = 0.0f, s1 = 0.0f;
            for (int dd = 0; dd < DDIM; ++dd) {
                const float w1d = agg_w1[snz * DDIM + dd];
                const float b1d = agg_b1[dd];
                const float h = fmaxf((float)c0 * w1d + b1d, 0.0f)
                              + fmaxf((float)c1 * w1d + b1d, 0.0f);
                s0 += h * agg_w2[dd * 2 + 0];
                s1 += h * agg_w2[dd * 2 + 1];
            }
            const float y0 = agg_b2[0] + 0.5f * s0;
            const float y1 = agg_b2[1] + 0.5f * s1;
            f4 v;
            v.x = 2.0f * enc_b2[q * 4 + 0];
            v.y = 2.0f * enc_b2[q * 4 + 1];
            v.z = 2.0f * enc_b2[q * 4 + 2];
            v.w = 2.0f * enc_b2[q * 4 + 3];
            for (int k = 0; k < DDIM; ++k) {
                const float w1e = enc_w1[k], b1e = enc_b1[k];
                const float gk = fmaxf(y0 * w1e + b1e, 0.0f)
                               + fmaxf(y1 * w1e + b1e, 0.0f);
                v.x += gk * enc_w2[k * DDIM + q * 4 + 0];
                v.y += gk * enc_w2[k * DDIM + q * 4 + 1];
                v.z += gk * enc_w2[k * DDIM + q * 4 + 2];
                v.w += gk * enc_w2[k * DDIM + q * 4 + 3];
            }
            out4[ent.x * 32u + q] = v;
        }
    }
}

extern "C" void kernel_launch(void* const* d_in, const int* in_sizes, int n_in,
                              void* d_out, int out_size, void* d_ws, size_t ws_size,
                              hipStream_t stream)
{
    const int* src_ids = (const int*)d_in[0];
    const int* dst_ids = (const int*)d_in[1];
    const int* src_sn  = (const int*)d_in[2];
    const int* dst_sn  = (const int*)d_in[3];
    const float* agg_w1 = (const float*)d_in[5];
    const float* agg_b1 = (const float*)d_in[6];
    const float* agg_w2 = (const float*)d_in[7];
    const float* agg_b2 = (const float*)d_in[8];
    const float* enc_w1 = (const float*)d_in[9];
    const float* enc_b1 = (const float*)d_in[10];
    const float* enc_w2 = (const float*)d_in[11];
    const float* enc_b2 = (const float*)d_in[12];
    float* out = (float*)d_out;

    // ws: rowinfo[131072] u32 | table[2048*128] f32 | slowcnt[64] u32 |
    //     slowbuf[64*2048] uint2
    unsigned int* rowinfo = (unsigned int*)d_ws;
    float* table = (float*)(rowinfo + NUNITS);
    unsigned int* slowcnt = (unsigned int*)(table + 2048 * DDIM);
    uint2* slowbuf = (uint2*)(slowcnt + 64);

    prep_kernel<<<NBATCH + 128, 1024, 0, stream>>>(
        src_ids, dst_ids, src_sn, dst_sn,
        agg_w1, agg_b1, agg_w2, agg_b2,
        enc_w1, enc_b1, enc_w2, enc_b2,
        rowinfo, table, slowcnt, slowbuf);

    gather_fix_kernel<<<NGBLK + NBATCH, 256, 0, stream>>>(
        rowinfo, table, slowcnt, slowbuf,
        agg_w1, agg_b1, agg_w2, agg_b2,
        enc_w1, enc_b1, enc_w2, enc_b2, out);
}